// Round 5
// baseline (113.545 us; speedup 1.0000x reference)
//
#include <hip/hip_runtime.h>

// Polyphase resample (up=3, down=2, F=1023) as bf16 MFMA Toeplitz GEMM,
// correlation form with FORWARD x layout:
//
//   out[3s+r] = sum_u g_r[u] * x[2s - 210 + u],  g_r[u] = hh_r[413-u]
//   hh_0[tau]=3h[3t-2], hh_1[tau]=3h[3t], hh_2[tau]=3h[3t+2], t=tau-32
//   (g_r support: u in [40,381])
//
// MFMA 32x32x16 bf16, s = s0 + 1024*wave + m + 32*n  (m,n in [0,32)):
//   A[m][k] = g_r[16q - 2m + k]           (prebuilt per-lane table in d_ws)
//   B[k][n] = x[2s0 + 2048*wave + 64n - 210 + 16q + k]   (forward, bf16 LDS)
//   D[m][n] = out_r[s], accumulate q = 2..27 (26 iters; covers u in [40,381])
// A lanes: m=lane&31, k=8*(lane>>5)+j.  B lanes: n=lane&31, k=8*(lane>>5)+j.
// C/D: col=lane&31, row=(reg&3)+8*(reg>>2)+4*(lane>>5)   [verified m74/m101]
//
// R5: forward layout kills the reversal (staging = 2 aligned float4 loads +
// add/perm bf16 pack per 8 floats); 32x32 halves B LDS reads; LDS = 17.3 KB.

typedef __attribute__((ext_vector_type(8)))  short bf16x8;
typedef __attribute__((ext_vector_type(16))) float f32x16;

constexpr int SBLK   = 4096;       // s-values per block (4 waves x 1024)
constexpr int NQ     = 26;         // q = 2..27
constexpr int NGROUP = 1073;       // 8-float staging groups per block
constexpr int LDSSEG = 1080;       // swizzled 16B segments (17280 B)
constexpr int AFE    = NQ * 192;   // A-table uint4 entries = 4992

__device__ __forceinline__ unsigned short f2bf_rne(float f) {
    union { float f; unsigned u; } c; c.f = f;
    return (unsigned short)((c.u + 0x7FFFu + ((c.u >> 16) & 1u)) >> 16);
}
// pack two f32 -> two bf16 (round-to-nearest, ties up): add 0x8000, take hi16
__device__ __forceinline__ unsigned pk2(float a, float b) {
    unsigned ua = __builtin_bit_cast(unsigned, a) + 0x8000u;
    unsigned ub = __builtin_bit_cast(unsigned, b) + 0x8000u;
    return __builtin_amdgcn_perm(ub, ua, 0x07060302);  // [ua.hi16, ub.hi16]
}
__device__ __forceinline__ int swz(int seg) { return seg ^ ((seg >> 3) & 7); }

// ---- pre-kernel: block-invariant A-fragment table -> d_ws ----
__global__ __launch_bounds__(256)
void build_afr_kernel(const float* __restrict__ h, uint4* __restrict__ afr)
{
    const int e = blockIdx.x * 256 + threadIdx.x;
    if (e >= AFE) return;
    const int qq   = e / 192;            // 0..25 -> q = qq+2
    const int rem  = e - qq * 192;
    const int r    = rem >> 6;
    const int lane = rem & 63;
    const int m    = lane & 31;
    const int hh   = lane >> 5;
    const int ub   = 16 * (qq + 2) - 2 * m + 8 * hh;   // u for j=0
    unsigned w[4];
    #pragma unroll
    for (int jp = 0; jp < 4; ++jp) {
        unsigned short half[2];
        #pragma unroll
        for (int uu = 0; uu < 2; ++uu) {
            const int u   = ub + 2 * jp + uu;
            const int t   = 381 - u;
            const int hix = (r == 0) ? 3 * t - 2 : ((r == 1) ? 3 * t : 3 * t + 2);
            half[uu] = (t >= 0 && hix >= 0 && hix < 1023) ? f2bf_rne(3.0f * h[hix])
                                                          : (unsigned short)0;
        }
        w[jp] = (unsigned)half[0] | ((unsigned)half[1] << 16);
    }
    afr[e] = make_uint4(w[0], w[1], w[2], w[3]);
}

__global__ __launch_bounds__(256, 4)
void resample_mfma_kernel(const float* __restrict__ x,
                          const uint4* __restrict__ afr,
                          float* __restrict__ out, int N)
{
    // bf16 x window, forward order, XOR-swizzled 16B segments.
    // slot s holds x[G0 + s], G0 = 2*s0 - 218 (slot of B-frag base == 0 mod 8)
    __shared__ __align__(16) unsigned short xb[LDSSEG * 8];

    const int tid = threadIdx.x;
    const int s0  = blockIdx.x * SBLK;
    const int A0  = 2 * s0 - 212;     // staging origin (16B-aligned in x)
    char* lb = (char*)xb;

    // ---- stage: group g = floats x[A0+8g .. A0+8g+7] -> slots 8g+6..8g+13
    //      pieces: b32 @ seg g off 12 | b64 @ seg g+1 off 0 | b32 @ seg g+1 off 8
    for (int it = 0; it < 5; ++it) {
        const int g = tid + 256 * it;
        if (g >= NGROUP) break;
        const int gb = A0 + 8 * g;
        float f[8];
        if (gb >= 0 && gb + 7 < N) {
            const float4 lo = *reinterpret_cast<const float4*>(x + gb);
            const float4 hi = *reinterpret_cast<const float4*>(x + gb + 4);
            f[0]=lo.x; f[1]=lo.y; f[2]=lo.z; f[3]=lo.w;
            f[4]=hi.x; f[5]=hi.y; f[6]=hi.z; f[7]=hi.w;
        } else {
            #pragma unroll
            for (int e = 0; e < 8; ++e) {
                const int idx = gb + e;
                f[e] = (idx >= 0 && idx < N) ? x[idx] : 0.0f;
            }
        }
        const unsigned p01 = pk2(f[0], f[1]);
        const unsigned p23 = pk2(f[2], f[3]);
        const unsigned p45 = pk2(f[4], f[5]);
        const unsigned p67 = pk2(f[6], f[7]);
        *reinterpret_cast<unsigned*>(lb + 16 * swz(g) + 12)    = p01;
        *reinterpret_cast<uint2*>  (lb + 16 * swz(g + 1))      = make_uint2(p23, p45);
        *reinterpret_cast<unsigned*>(lb + 16 * swz(g + 1) + 8) = p67;
    }
    __syncthreads();

    const int wave = tid >> 6;
    const int lane = tid & 63;
    const int n    = lane & 31;
    const int hh   = lane >> 5;

    f32x16 acc[3] = {};

    // B slot base (j=0): 2048*wave + 64n + 8*hh + 8 + 16q  -> seg = slot>>3
    const int segbase = 256 * wave + 8 * n + hh + 1;
    const uint4* ap = afr + lane;

    #pragma unroll
    for (int qq = 0; qq < NQ; ++qq) {
        const int seg = segbase + 2 * (qq + 2);
        const bf16x8 B = __builtin_bit_cast(
            bf16x8, *reinterpret_cast<const uint4*>(lb + 16 * swz(seg)));
        #pragma unroll
        for (int r = 0; r < 3; ++r) {
            const bf16x8 A = __builtin_bit_cast(bf16x8, ap[qq * 192 + r * 64]);
            acc[r] = __builtin_amdgcn_mfma_f32_32x32x16_bf16(A, B, acc[r], 0, 0, 0);
        }
    }

    // ---- epilogue: for c=0..3, rows m = {0..3}+8c+4hh, col n:
    //      out offsets 3*(s0+1024*wave+m+32n)+r = base + 24c + {0..11} contiguous
    float* ob = out + 3 * s0 + 3072 * wave + 12 * hh + 96 * n;
    #pragma unroll
    for (int c = 0; c < 4; ++c) {
        float* p = ob + 24 * c;
        *reinterpret_cast<float4*>(p) =
            make_float4(acc[0][4*c],   acc[1][4*c],   acc[2][4*c],   acc[0][4*c+1]);
        *reinterpret_cast<float4*>(p + 4) =
            make_float4(acc[1][4*c+1], acc[2][4*c+1], acc[0][4*c+2], acc[1][4*c+2]);
        *reinterpret_cast<float4*>(p + 8) =
            make_float4(acc[2][4*c+2], acc[0][4*c+3], acc[1][4*c+3], acc[2][4*c+3]);
    }
}

extern "C" void kernel_launch(void* const* d_in, const int* in_sizes, int n_in,
                              void* d_out, int out_size, void* d_ws, size_t ws_size,
                              hipStream_t stream)
{
    const float* x = (const float*)d_in[0];
    // d_in[1] = up (3), d_in[2] = down (2) — structure hard-coded for 3/2, F=1023
    const float* h = (const float*)d_in[3];
    float* out = (float*)d_out;
    uint4* afr = (uint4*)d_ws;         // 79872 B

    const int N    = in_sizes[0];
    const int S    = out_size / 3;     // 4194304
    const int nblk = S / SBLK;         // 1024 (exact)

    build_afr_kernel<<<(AFE + 255) / 256, 256, 0, stream>>>(h, afr);
    resample_mfma_kernel<<<nblk, 256, 0, stream>>>(x, afr, out, N);
}

// Round 6
// 111.602 us; speedup vs baseline: 1.0174x; 1.0174x over previous
//
#include <hip/hip_runtime.h>

// Polyphase resample (up=3, down=2, F=1023) as bf16 MFMA Toeplitz GEMM,
// correlation form, forward x layout, SINGLE-WAVE WORKGROUPS (barrier-free).
//
//   out[3s+r] = sum_u g_r[u] * x[2s - 210 + u],  g_r[u] = hh_r[413-u]
//   hh_0[tau]=3h[3t-2], hh_1[tau]=3h[3t], hh_2[tau]=3h[3t+2], t=tau-32
//
// MFMA 32x32x16 bf16, one D-tile per block: s = 1024*blk + m + 32*n:
//   A[m][k] = g_r[16q - 2m + k]         (prebuilt per-lane table in d_ws, L2-hot)
//   B[k][n] = x[2*s0 + 64n - 210 + 16q + k]   (bf16, wave-private LDS window)
//   D[m][n] = out_r[s], q = 2..27.  A lanes m=lane&31,k=8*(lane>>5)+j; B same.
//   C/D: col=lane&31, row=(reg&3)+8*(reg>>2)+4*(lane>>5)
//
// R6: workgroup == wavefront -> no __syncthreads anywhere; 16 blocks/CU
// free-run so stage/compute/store phases of different waves overlap (fixes
// the lockstep latency-bound plateau of R2-R5). Staging loads all batched
// before packing; q-loop unroll 2 (A prefetch without VGPR blowup).

typedef __attribute__((ext_vector_type(8)))  short bf16x8;
typedef __attribute__((ext_vector_type(16))) float f32x16;

constexpr int NQ     = 26;         // q = 2..27
constexpr int NGROUP = 306;        // 8-float staging groups per block
constexpr int LDSSEG = 312;        // swizzled 16B segments (4992 B)
constexpr int AFE    = NQ * 192;   // A-table uint4 entries = 4992

__device__ __forceinline__ unsigned short f2bf_rne(float f) {
    union { float f; unsigned u; } c; c.f = f;
    return (unsigned short)((c.u + 0x7FFFu + ((c.u >> 16) & 1u)) >> 16);
}
// pack two f32 -> two bf16 (round-to-nearest): add 0x8000, take hi16 of each
__device__ __forceinline__ unsigned pk2(float a, float b) {
    unsigned ua = __builtin_bit_cast(unsigned, a) + 0x8000u;
    unsigned ub = __builtin_bit_cast(unsigned, b) + 0x8000u;
    return __builtin_amdgcn_perm(ub, ua, 0x07060302);  // [a.hi16 | b.hi16]
}
__device__ __forceinline__ int swz(int seg) { return seg ^ ((seg >> 3) & 7); }

// ---- pre-kernel: block-invariant A-fragment table -> d_ws ----
__global__ __launch_bounds__(256)
void build_afr_kernel(const float* __restrict__ h, uint4* __restrict__ afr)
{
    const int e = blockIdx.x * 256 + threadIdx.x;
    if (e >= AFE) return;
    const int qq   = e / 192;            // 0..25 -> q = qq+2
    const int rem  = e - qq * 192;
    const int r    = rem >> 6;
    const int lane = rem & 63;
    const int m    = lane & 31;
    const int hh   = lane >> 5;
    const int ub   = 16 * (qq + 2) - 2 * m + 8 * hh;   // u for j=0
    unsigned w[4];
    #pragma unroll
    for (int jp = 0; jp < 4; ++jp) {
        unsigned short half[2];
        #pragma unroll
        for (int uu = 0; uu < 2; ++uu) {
            const int u   = ub + 2 * jp + uu;
            const int t   = 381 - u;
            const int hix = (r == 0) ? 3 * t - 2 : ((r == 1) ? 3 * t : 3 * t + 2);
            half[uu] = (t >= 0 && hix >= 0 && hix < 1023) ? f2bf_rne(3.0f * h[hix])
                                                          : (unsigned short)0;
        }
        w[jp] = (unsigned)half[0] | ((unsigned)half[1] << 16);
    }
    afr[e] = make_uint4(w[0], w[1], w[2], w[3]);
}

__global__ __launch_bounds__(64, 4)
void resample_mfma_kernel(const float* __restrict__ x,
                          const uint4* __restrict__ afr,
                          float* __restrict__ out, int N)
{
    // wave-private bf16 x window, forward order, XOR-swizzled 16B segments.
    // slot p holds x[G0 + p], G0 = 2*s0 - 218.
    __shared__ __align__(16) unsigned short xb[LDSSEG * 8];
    char* lb = (char*)xb;

    const int lane = threadIdx.x;      // block == one wave
    const int s0   = blockIdx.x * 1024;
    const int A0   = 2 * s0 - 212;     // staging origin (16B-aligned in x)

    // ---- staging: batch all global loads first, then pack+write LDS ----
    float4 lo[5], hi[5];
    #pragma unroll
    for (int i = 0; i < 5; ++i) {
        const int g  = lane + 64 * i;
        const int gb = A0 + 8 * g;
        if (g < NGROUP && gb >= 0 && gb + 7 < N) {
            lo[i] = *reinterpret_cast<const float4*>(x + gb);
            hi[i] = *reinterpret_cast<const float4*>(x + gb + 4);
        } else {
            float f[8];
            #pragma unroll
            for (int e = 0; e < 8; ++e) {
                const int idx = gb + e;
                f[e] = (g < NGROUP && idx >= 0 && idx < N) ? x[idx] : 0.0f;
            }
            lo[i] = make_float4(f[0], f[1], f[2], f[3]);
            hi[i] = make_float4(f[4], f[5], f[6], f[7]);
        }
    }
    #pragma unroll
    for (int i = 0; i < 5; ++i) {
        const int g = lane + 64 * i;
        if (g >= NGROUP) continue;
        // group g = x[A0+8g .. +7] -> slots 8g+6 .. 8g+13
        const unsigned p01 = pk2(lo[i].x, lo[i].y);
        const unsigned p23 = pk2(lo[i].z, lo[i].w);
        const unsigned p45 = pk2(hi[i].x, hi[i].y);
        const unsigned p67 = pk2(hi[i].z, hi[i].w);
        *reinterpret_cast<unsigned*>(lb + 16 * swz(g) + 12)    = p01;
        *reinterpret_cast<uint2*>  (lb + 16 * swz(g + 1))      = make_uint2(p23, p45);
        *reinterpret_cast<unsigned*>(lb + 16 * swz(g + 1) + 8) = p67;
    }
    // no barrier: same-wave LDS dependency (compiler inserts lgkmcnt waits)

    const int n  = lane & 31;
    const int hh = lane >> 5;

    f32x16 acc[3] = {};

    // B slot (j=0): 64n + 8hh + 8 + 16q  -> seg = 8n + hh + 1 + 2q
    const int segbase  = 8 * n + hh + 1 + 4;   // q = qq+2
    const uint4* aq = afr + lane;

    #pragma unroll 2
    for (int qq = 0; qq < NQ; ++qq) {
        const int seg = segbase + 2 * qq;
        const bf16x8 B = __builtin_bit_cast(
            bf16x8, *reinterpret_cast<const uint4*>(lb + 16 * swz(seg)));
        const bf16x8 A0f = __builtin_bit_cast(bf16x8, aq[0]);
        const bf16x8 A1f = __builtin_bit_cast(bf16x8, aq[64]);
        const bf16x8 A2f = __builtin_bit_cast(bf16x8, aq[128]);
        acc[0] = __builtin_amdgcn_mfma_f32_32x32x16_bf16(A0f, B, acc[0], 0, 0, 0);
        acc[1] = __builtin_amdgcn_mfma_f32_32x32x16_bf16(A1f, B, acc[1], 0, 0, 0);
        acc[2] = __builtin_amdgcn_mfma_f32_32x32x16_bf16(A2f, B, acc[2], 0, 0, 0);
        aq += 192;
    }

    // ---- epilogue: rows m = i + 8c + 4hh, col n:
    //      out idx = 3*s0 + 12hh + 96n + 24c + (3i + r) -> 12 contiguous / c
    float* ob = out + 3 * s0 + 12 * hh + 96 * n;
    #pragma unroll
    for (int c = 0; c < 4; ++c) {
        float* p = ob + 24 * c;
        *reinterpret_cast<float4*>(p) =
            make_float4(acc[0][4*c],   acc[1][4*c],   acc[2][4*c],   acc[0][4*c+1]);
        *reinterpret_cast<float4*>(p + 4) =
            make_float4(acc[1][4*c+1], acc[2][4*c+1], acc[0][4*c+2], acc[1][4*c+2]);
        *reinterpret_cast<float4*>(p + 8) =
            make_float4(acc[2][4*c+2], acc[0][4*c+3], acc[1][4*c+3], acc[2][4*c+3]);
    }
}

extern "C" void kernel_launch(void* const* d_in, const int* in_sizes, int n_in,
                              void* d_out, int out_size, void* d_ws, size_t ws_size,
                              hipStream_t stream)
{
    const float* x = (const float*)d_in[0];
    // d_in[1] = up (3), d_in[2] = down (2) — structure hard-coded for 3/2, F=1023
    const float* h = (const float*)d_in[3];
    float* out = (float*)d_out;
    uint4* afr = (uint4*)d_ws;         // 79872 B

    const int N    = in_sizes[0];
    const int S    = out_size / 3;     // 4194304
    const int nblk = S / 1024;         // 4096 (exact)

    build_afr_kernel<<<(AFE + 255) / 256, 256, 0, stream>>>(h, afr);
    resample_mfma_kernel<<<nblk, 64, 0, stream>>>(x, afr, out, N);
}